// Round 18
// baseline (30.522 us; speedup 1.0000x reference)
//
#include <hip/hip_runtime.h>
#include <hip/hip_fp16.h>
#include <math.h>

#define HW 16384
#define NPROJ 100
#define NB 8
#define EPSV 1e-6f

__device__ inline float4 add4(float4 a, float4 b) {
    return make_float4(a.x + b.x, a.y + b.y, a.z + b.z, a.w + b.w);
}
__device__ inline float4 sub4(float4 a, float4 b) {
    return make_float4(a.x - b.x, a.y - b.y, a.z - b.z, a.w - b.w);
}
__device__ inline float4 mul4(float4 a, float4 b) {
    return make_float4(a.x * b.x, a.y * b.y, a.z * b.z, a.w * b.w);
}
__device__ inline float4 shfl_up4(float4 v, int off) {
    return make_float4(__shfl_up(v.x, off), __shfl_up(v.y, off),
                       __shfl_up(v.z, off), __shfl_up(v.w, off));
}
__device__ inline float4 shfl_up4w(float4 v, int off, int w) {
    return make_float4(__shfl_up(v.x, off, w), __shfl_up(v.y, off, w),
                       __shfl_up(v.z, off, w), __shfl_up(v.w, off, w));
}
__device__ inline unsigned int packh2(float a, float b) {
    __half2 h = __floats2half2_rn(a, b);
    return *reinterpret_cast<unsigned int*>(&h);
}
__device__ inline float2 unpackh2(unsigned int w) {
    __half2 h = *reinterpret_cast<__half2*>(&w);
    return make_float2(__low2float(h), __high2float(h));
}

// K1: one thread per pixel. Packs RAW (Xs = x0+x1+x2, Y0) as fp16x8 per pixel
// in channel-group-major uint4 pairs (needs no global sums), and emits
// per-block partials {sum Xs_b, sum Y0_b, max/argmax x0_b} for each batch.
// Block 0 zeroes the output.
__global__ __launch_bounds__(256) void prep_kernel(const float* __restrict__ X,
                                                   const float* __restrict__ Y,
                                                   uint4* __restrict__ Zraw,
                                                   float* __restrict__ Pmax,
                                                   int* __restrict__ Pidx,
                                                   float* __restrict__ Psx,
                                                   float* __restrict__ Psy,
                                                   float* __restrict__ out) {
    const int blk = blockIdx.x;
    const int tid = threadIdx.x, lane = tid & 63, wid = tid >> 6;
    const int p = blk * 256 + tid;
    if (blk == 0 && tid == 0) out[0] = 0.0f;  // consumed only by wproj atomics

    float xs[8], yy[8], x0v[8];
#pragma unroll
    for (int b = 0; b < 8; ++b) {
        const float* xb = X + (size_t)b * 3 * HW;
        float x0 = xb[p], x1 = xb[HW + p], x2 = xb[2 * HW + p];
        x0v[b] = x0;
        xs[b] = x0 + x1 + x2;
        yy[b] = Y[(size_t)b * 3 * HW + p];
    }
    Zraw[2 * p] = make_uint4(packh2(xs[0], xs[1]), packh2(xs[2], xs[3]),
                             packh2(yy[0], yy[1]), packh2(yy[2], yy[3]));
    Zraw[2 * p + 1] = make_uint4(packh2(xs[4], xs[5]), packh2(xs[6], xs[7]),
                                 packh2(yy[4], yy[5]), packh2(yy[6], yy[7]));

    __shared__ float smv[8][4], ssx[8][4], ssy[8][4];
    __shared__ int smi[8][4];
#pragma unroll
    for (int b = 0; b < 8; ++b) {
        float mv = x0v[b], sx = xs[b], sy = yy[b];
        int mi = p;
#pragma unroll
        for (int off = 32; off > 0; off >>= 1) {
            float ov = __shfl_down(mv, off);
            int oi = __shfl_down(mi, off);
            sx += __shfl_down(sx, off);
            sy += __shfl_down(sy, off);
            if (ov > mv || (ov == mv && oi < mi)) { mv = ov; mi = oi; }
        }
        if (lane == 0) { smv[b][wid] = mv; smi[b][wid] = mi;
                         ssx[b][wid] = sx; ssy[b][wid] = sy; }
    }
    __syncthreads();
    if (tid < 8) {
        float mv = smv[tid][0], sx = ssx[tid][0], sy = ssy[tid][0];
        int mi = smi[tid][0];
        for (int w = 1; w < 4; ++w) {
            float ov = smv[tid][w];
            int oi = smi[tid][w];
            if (ov > mv || (ov == mv && oi < mi)) { mv = ov; mi = oi; }
            sx += ssx[tid][w];
            sy += ssy[tid][w];
        }
        Pmax[tid * 64 + blk] = mv;
        Pidx[tid * 64 + blk] = mi;
        Psx[tid * 64 + blk] = sx;
        Psy[tid * 64 + blk] = sy;
    }
}

// K2: two blocks per projection (half h owns sorted positions [h*8192,...)).
// Prologue: one wave per batch reduces the 64 partials -> invX/invY/fa/fi in
// LDS (parallel with ce build). Phase 1: r14's Ptab prefix-table ranksort.
// Phase 2: per pixel gather BOTH adjacent uint4 (same cache line), convert
// raw->w = Xs*invX - Y0*invY immediately, single-pass 8-channel register scan,
// CDF integral. Cross-half carry via sum(w) = -sum(fa*invX) (0 on hot path).
// EPS-fix handled as a step delta at analytically-computed rank (cold path).
__global__ __launch_bounds__(1024)
__attribute__((amdgpu_waves_per_eu(4, 4)))
void wproj_kernel(const float* __restrict__ proj,
                  const uint4* __restrict__ Zraw,
                  const float* __restrict__ Pmax,
                  const int* __restrict__ Pidx,
                  const float* __restrict__ Psx,
                  const float* __restrict__ Psy,
                  float* __restrict__ out) {
    __shared__ int ce[255];                     // c*2 | e
    __shared__ unsigned short Ptab[256 * 128];  // 64 KiB prefix table
    __shared__ int psum[8 * 128];
    __shared__ unsigned short sidT[8192];       // own half
    __shared__ float4 lwa[17], lwb[17];
    __shared__ float lred[16];
    __shared__ float sInvX[8], sInvY[8], sFa[8];
    __shared__ int sFi[8], sRfi[8];
    __shared__ int sBound, sAnyTie, sAnyFix;

    const int jp = blockIdx.x >> 1;
    const int h = blockIdx.x & 1;
    const int tid = threadIdx.x, lane = tid & 63, wid = tid >> 6;
    float a = proj[jp];
    float b = proj[NPROJ + jp];
    float inv = 1.0f / sqrtf(a * a + b * b);
    const float an = a * inv, bn = b * inv;
    const float ap = fabsf(an), bp = fabsf(bn);
    const bool flipi = (an < 0.0f), flipj = (bn < 0.0f);

    if (tid == 1023) { sAnyTie = 0; sAnyFix = 0; sBound = 0; }
    __syncthreads();

    // prologue: batch b reduced by wave b (tid 64b..64b+63)
    if (tid < 512) {
        const int b2 = wid, c = lane;
        float mv = Pmax[b2 * 64 + c];
        int mi = Pidx[b2 * 64 + c];
        float sx = Psx[b2 * 64 + c];
        float sy = Psy[b2 * 64 + c];
#pragma unroll
        for (int off = 32; off > 0; off >>= 1) {
            float ov = __shfl_down(mv, off);
            int oi = __shfl_down(mi, off);
            float osx = __shfl_down(sx, off);
            float osy = __shfl_down(sy, off);
            if (ov > mv || (ov == mv && oi < mi)) { mv = ov; mi = oi; }
            sx += osx;
            sy += osy;
        }
        if (c == 0) {
            float fa = (mv < EPSV) ? (EPSV - mv) : 0.0f;
            sFa[b2] = fa;
            sFi[b2] = mi;
            sInvX[b2] = 1.0f / (sx + fa);
            sInvY[b2] = 1.0f / sy;
            if (fa > 0.0f) sAnyFix = 1;
        }
    }
    // ce build in parallel (threads 512..766)
    if (bp != 0.0f && tid >= 512 && tid < 767) {
        int t = tid - 512;
        int d = t - 127;
        double v = (double)d * ((double)ap / (double)bp);
        double cv = ceil(v);
        int e = (cv == v) ? 1 : 0;
        int c = (int)fmin(fmax(cv, -128.0), 129.0);
        ce[t] = c * 2 + e;
        if (e && d >= 1) sAnyTie = 1;
    }
    __syncthreads();

    const float4 iXa = make_float4(sInvX[0], sInvX[1], sInvX[2], sInvX[3]);
    const float4 iXb = make_float4(sInvX[4], sInvX[5], sInvX[6], sInvX[7]);
    const float4 iYa = make_float4(sInvY[0], sInvY[1], sInvY[2], sInvY[3]);
    const float4 iYb = make_float4(sInvY[4], sInvY[5], sInvY[6], sInvY[7]);

    // ---- phase 1: ranksort (r14 Ptab version) ----
    if (bp == 0.0f) {
        for (int t = tid; t < HW; t += 1024) {
            int i2 = t >> 7, j2 = t & 127;
            int ii = flipi ? 127 - i2 : i2;
            int jj = flipj ? 127 - j2 : j2;
            int idv = ii * 128 + jj;
            if (t == 8192) sBound = idv;
            int q = t - (h << 13);
            if ((unsigned)q < 8192u)
                sidT[(q & 7) * 1024 + (q >> 3)] = (unsigned short)idv;
        }
        __syncthreads();
    } else {
        const int j2 = tid & 127;
        const int g = tid >> 7;
        const int jj = flipj ? 127 - j2 : j2;
        const bool anyTie = (sAnyTie != 0);

        int lp[32];
        int tmask = 0;
        {
            int run = 0;
            const int dd0 = g * 32;
#pragma unroll
            for (int q = 0; q < 32; ++q) {
                int dd = dd0 + q;
                int cl = 0;
                if (dd < 255) {
                    int c = ce[dd] >> 1;
                    cl = min(max(c + j2, 0), 128);
                }
                run += cl;
                lp[q] = run;
            }
            int tcnt = 0;
            if (anyTie) {
#pragma unroll
                for (int q = 1; q <= 16; ++q) {
                    int i2p = g * 16 + q;
                    if (i2p <= 127) {
                        int v = ce[i2p + 127];
                        if (v & 1) {
                            int tj = j2 + (v >> 1);
                            if (tj >= 0 && tj < 128) { tmask |= (1 << q); tcnt++; }
                        }
                    }
                }
            }
            psum[g * 128 + j2] = (run << 5) | tcnt;
        }
        __syncthreads();

        int carryP = 0, carryT = 0;
        for (int g2 = 0; g2 < g; ++g2) {
            int v = psum[g2 * 128 + j2];
            carryP += (v >> 5);
            carryT += (v & 31);
        }
        if (g == 0) Ptab[j2] = 0;
        {
            const int dd0 = g * 32;
#pragma unroll
            for (int q = 0; q < 32; ++q) {
                int dd = dd0 + q;
                if (dd < 255)
                    Ptab[(dd + 1) * 128 + j2] = (unsigned short)(carryP + lp[q]);
            }
        }
        __syncthreads();

        int tsum = carryT;
        const int i2s = g * 16;
#pragma unroll
        for (int q = 0; q < 16; ++q) {
            int i2 = i2s + q;
            if (q > 0) tsum += (tmask >> q) & 1;
            int wsum = (int)Ptab[(i2 + 128) * 128 + j2] - (int)Ptab[i2 * 128 + j2];
            int pos = wsum + tsum;
            int ii = flipi ? 127 - i2 : i2;
            int idv = ii * 128 + jj;
            if (pos == 8192) sBound = idv;
            int ql = pos - (h << 13);
            if ((unsigned)ql < 8192u)
                sidT[(ql & 7) * 1024 + (ql >> 3)] = (unsigned short)idv;
        }
        __syncthreads();
    }

    // cold path: sorted position of the EPS-fix pixel per batch
    const bool anyFix = (sAnyFix != 0);
    if (anyFix) {
        if (tid < 8) {
            int fi = sFi[tid];
            int ii = fi >> 7, jj = fi & 127;
            int i2 = flipi ? 127 - ii : ii;
            int j2 = flipj ? 127 - jj : jj;
            if (bp == 0.0f) {
                sRfi[tid] = i2 * 128 + j2;
            } else {
                int wsum = 0;
                for (int dd = i2; dd < i2 + 128; ++dd)
                    wsum += min(max((ce[dd] >> 1) + j2, 0), 128);
                int tsum = 0;
                for (int i2p = 1; i2p <= i2; ++i2p) {
                    int v = ce[i2p + 127];
                    if (v & 1) {
                        int tj = j2 + (v >> 1);
                        if (tj >= 0 && tj < 128) tsum++;
                    }
                }
                sRfi[tid] = wsum + tsum;
            }
        }
        __syncthreads();
    }

    // ---- phase 2: thread owns local positions [8*tid, 8*tid+7] ----
    int ids[9];
#pragma unroll
    for (int m = 0; m < 8; ++m) ids[m] = (int)sidT[m * 1024 + tid];
    ids[8] = (tid < 1023) ? (int)sidT[tid + 1]
                          : ((h == 0) ? sBound : ids[7]);

    float dpc[8];
    {
        float pc_cur = (float)(ids[0] >> 7) * an + (float)(ids[0] & 127) * bn;
#pragma unroll
        for (int m = 0; m < 8; ++m) {
            int idn = ids[m + 1];
            float pc_nxt = (float)(idn >> 7) * an + (float)(idn & 127) * bn;
            dpc[m] = pc_nxt - pc_cur;
            pc_cur = pc_nxt;
        }
    }

    // gather both adjacent 16B words (same cache line) and convert to w
    float4 zva[8], zvb[8];
#pragma unroll
    for (int m = 0; m < 8; ++m) {
        uint4 r0 = Zraw[2 * ids[m]];
        uint4 r1 = Zraw[2 * ids[m] + 1];
        float2 x01 = unpackh2(r0.x), x23 = unpackh2(r0.y);
        float2 y01 = unpackh2(r0.z), y23 = unpackh2(r0.w);
        float2 x45 = unpackh2(r1.x), x67 = unpackh2(r1.y);
        float2 y45 = unpackh2(r1.z), y67 = unpackh2(r1.w);
        float4 xsA = make_float4(x01.x, x01.y, x23.x, x23.y);
        float4 ysA = make_float4(y01.x, y01.y, y23.x, y23.y);
        float4 xsB = make_float4(x45.x, x45.y, x67.x, x67.y);
        float4 ysB = make_float4(y45.x, y45.y, y67.x, y67.y);
        zva[m] = sub4(mul4(xsA, iXa), mul4(ysA, iYa));
        zvb[m] = sub4(mul4(xsB, iXb), mul4(ysB, iYb));
    }
#pragma unroll
    for (int m = 1; m < 8; ++m) {
        zva[m] = add4(zva[m], zva[m - 1]);
        zvb[m] = add4(zvb[m], zvb[m - 1]);
    }
    const float4 tota = zva[7], totb = zvb[7];

    float4 ia = tota, ib = totb;
#pragma unroll
    for (int off = 1; off < 64; off <<= 1) {
        float4 ua = shfl_up4(ia, off);
        float4 ub = shfl_up4(ib, off);
        if (lane >= off) { ia = add4(ia, ua); ib = add4(ib, ub); }
    }
    if (lane == 63) { lwa[wid] = ia; lwb[wid] = ib; }
    __syncthreads();
    if (tid < 16) {
        float4 va = lwa[tid], vb = lwb[tid];
        float4 sa = va, sb = vb;
#pragma unroll
        for (int off = 1; off < 16; off <<= 1) {
            float4 ua = shfl_up4w(sa, off, 16);
            float4 ub = shfl_up4w(sb, off, 16);
            if (tid >= off) { sa = add4(sa, ua); sb = add4(sb, ub); }
        }
        lwa[tid] = sub4(sa, va);
        lwb[tid] = sub4(sb, vb);
        if (tid == 15) { lwa[16] = sa; lwb[16] = sb; }
    }
    __syncthreads();

    float4 preA = add4(sub4(ia, tota), lwa[wid]);
    float4 preB = add4(sub4(ib, totb), lwb[wid]);
    if (h == 1) {
        // S(8191) = S_total - S_h1 ; S_total = -sum_b fa_b*invX_b (0 on hot path)
        preA = sub4(preA, lwa[16]);
        preB = sub4(preB, lwb[16]);
        if (anyFix) {
            preA = sub4(preA, make_float4(sFa[0] * sInvX[0], sFa[1] * sInvX[1],
                                          sFa[2] * sInvX[2], sFa[3] * sInvX[3]));
            preB = sub4(preB, make_float4(sFa[4] * sInvX[4], sFa[5] * sInvX[5],
                                          sFa[6] * sInvX[6], sFa[7] * sInvX[7]));
        }
    }

    float acc = 0.0f;
    if (!anyFix) {
#pragma unroll
        for (int m = 0; m < 8; ++m) {
            float4 cxa = add4(preA, zva[m]);
            float4 cxb = add4(preB, zvb[m]);
            float s8 = fabsf(cxa.x) + fabsf(cxa.y) + fabsf(cxa.z) + fabsf(cxa.w)
                     + fabsf(cxb.x) + fabsf(cxb.y) + fabsf(cxb.z) + fabsf(cxb.w);
            acc += s8 * dpc[m];
        }
    } else {
#pragma unroll
        for (int m = 0; m < 8; ++m) {
            float4 cxa = add4(preA, zva[m]);
            float4 cxb = add4(preB, zvb[m]);
            int gpos = (h << 13) + tid * 8 + m;
            if (gpos >= sRfi[0]) cxa.x += sFa[0] * sInvX[0];
            if (gpos >= sRfi[1]) cxa.y += sFa[1] * sInvX[1];
            if (gpos >= sRfi[2]) cxa.z += sFa[2] * sInvX[2];
            if (gpos >= sRfi[3]) cxa.w += sFa[3] * sInvX[3];
            if (gpos >= sRfi[4]) cxb.x += sFa[4] * sInvX[4];
            if (gpos >= sRfi[5]) cxb.y += sFa[5] * sInvX[5];
            if (gpos >= sRfi[6]) cxb.z += sFa[6] * sInvX[6];
            if (gpos >= sRfi[7]) cxb.w += sFa[7] * sInvX[7];
            float s8 = fabsf(cxa.x) + fabsf(cxa.y) + fabsf(cxa.z) + fabsf(cxa.w)
                     + fabsf(cxb.x) + fabsf(cxb.y) + fabsf(cxb.z) + fabsf(cxb.w);
            acc += s8 * dpc[m];
        }
    }

    // block reduce
#pragma unroll
    for (int off = 32; off > 0; off >>= 1) acc += __shfl_down(acc, off);
    if (lane == 0) lred[wid] = acc;
    __syncthreads();
    if (tid == 0) {
        float r2 = 0.0f;
        for (int w = 0; w < 16; ++w) r2 += lred[w];
        atomicAdd(out, r2 * (1.0f / NPROJ));
    }
}

extern "C" void kernel_launch(void* const* d_in, const int* in_sizes, int n_in,
                              void* d_out, int out_size, void* d_ws, size_t ws_size,
                              hipStream_t stream) {
    const float* X = (const float*)d_in[0];
    const float* Y = (const float*)d_in[1];
    const float* proj = (const float*)d_in[2];
    float* out = (float*)d_out;

    char* ws = (char*)d_ws;
    size_t off = 0;
    uint4* Zraw = (uint4*)(ws + off);   off += (size_t)2 * HW * sizeof(uint4);
    float* Pmax = (float*)(ws + off);   off += NB * 64 * sizeof(float);
    int* Pidx = (int*)(ws + off);       off += NB * 64 * sizeof(int);
    float* Psx = (float*)(ws + off);    off += NB * 64 * sizeof(float);
    float* Psy = (float*)(ws + off);    off += NB * 64 * sizeof(float);

    prep_kernel<<<HW / 256, 256, 0, stream>>>(X, Y, Zraw, Pmax, Pidx, Psx, Psy, out);
    wproj_kernel<<<NPROJ * 2, 1024, 0, stream>>>(proj, Zraw, Pmax, Pidx, Psx, Psy, out);
}

// Round 19
// 25.641 us; speedup vs baseline: 1.1903x; 1.1903x over previous
//
#include <hip/hip_runtime.h>
#include <hip/hip_fp16.h>
#include <math.h>

#define HW 16384
#define NPROJ 100
#define NB 8
#define NCH 32
#define CHLEN 512
#define EPSV 1e-6f

__device__ inline float4 add4(float4 a, float4 b) {
    return make_float4(a.x + b.x, a.y + b.y, a.z + b.z, a.w + b.w);
}
__device__ inline float4 sub4(float4 a, float4 b) {
    return make_float4(a.x - b.x, a.y - b.y, a.z - b.z, a.w - b.w);
}
__device__ inline float4 shfl_up4(float4 v, int off) {
    return make_float4(__shfl_up(v.x, off), __shfl_up(v.y, off),
                       __shfl_up(v.z, off), __shfl_up(v.w, off));
}
__device__ inline float4 shfl_up4w(float4 v, int off, int w) {
    return make_float4(__shfl_up(v.x, off, w), __shfl_up(v.y, off, w),
                       __shfl_up(v.z, off, w), __shfl_up(v.w, off, w));
}
__device__ inline unsigned int packh2(float a, float b) {
    __half2 h = __floats2half2_rn(a, b);
    return *reinterpret_cast<unsigned int*>(&h);
}
__device__ inline float2 unpackh2(unsigned int w) {
    __half2 h = *reinterpret_cast<__half2*>(&w);
    return make_float2(__low2float(h), __high2float(h));
}

// Stage 1: per-(batch, chunk) partials: Xs = x0+x1+x2 (stored), sum(Xs), sum(y0),
// chunk max/argmax of x0 (first-occurrence). Block 0 zeroes the output.
__global__ __launch_bounds__(256) void partial_kernel(const float* __restrict__ X,
                                                      const float* __restrict__ Y,
                                                      float* __restrict__ Xs,
                                                      float* __restrict__ Pmax,
                                                      int* __restrict__ Pidx,
                                                      float* __restrict__ Psx,
                                                      float* __restrict__ Psy,
                                                      float* __restrict__ out) {
    const int blk = blockIdx.x;
    const int b = blk >> 5, c = blk & 31;
    const int tid = threadIdx.x, lane = tid & 63, wid = tid >> 6;
    if (blk == 0 && tid == 0) out[0] = 0.0f;  // consumed only by wproj (later kernel)
    const float* xb = X + (size_t)b * 3 * HW;
    const float* yb = Y + (size_t)b * 3 * HW;
    const int base = c * CHLEN;

    float mv = -INFINITY;
    int mi = 0;
    float sx = 0.0f, sy = 0.0f;
#pragma unroll
    for (int k = 0; k < 2; ++k) {
        int p = base + k * 256 + tid;
        float x0 = xb[p], x1 = xb[HW + p], x2 = xb[2 * HW + p], y0 = yb[p];
        float s = x0 + x1 + x2;
        Xs[(size_t)b * HW + p] = s;
        sx += s;
        sy += y0;
        if (x0 > mv) { mv = x0; mi = p; }   // strict > keeps earliest p
    }
#pragma unroll
    for (int off = 32; off > 0; off >>= 1) {
        float ov = __shfl_down(mv, off);
        int oi = __shfl_down(mi, off);
        sx += __shfl_down(sx, off);
        sy += __shfl_down(sy, off);
        if (ov > mv || (ov == mv && oi < mi)) { mv = ov; mi = oi; }
    }
    __shared__ float lmv[4], lsx[4], lsy[4];
    __shared__ int lmi[4];
    if (lane == 0) { lmv[wid] = mv; lmi[wid] = mi; lsx[wid] = sx; lsy[wid] = sy; }
    __syncthreads();
    if (tid == 0) {
        for (int w = 1; w < 4; ++w) {
            if (lmv[w] > lmv[0] || (lmv[w] == lmv[0] && lmi[w] < lmi[0])) {
                lmv[0] = lmv[w];
                lmi[0] = lmi[w];
            }
            lsx[0] += lsx[w];
            lsy[0] += lsy[w];
        }
        Pmax[blk] = lmv[0];
        Pidx[blk] = lmi[0];
        Psx[blk] = lsx[0];
        Psy[blk] = lsy[0];
    }
}

// Stage 2 (combine folded in): every block redundantly reduces the 8x32 partials,
// then builds Zh[p] = packed fp16 x8: (Xs+fix)*invX - Y0*invY, pixel-major 16B.
__global__ __launch_bounds__(256) void zprep_kernel(const float* __restrict__ Pmax,
                                                    const int* __restrict__ Pidx,
                                                    const float* __restrict__ Psx,
                                                    const float* __restrict__ Psy,
                                                    const float* __restrict__ Xs,
                                                    const float* __restrict__ Y,
                                                    uint4* __restrict__ Zh) {
    __shared__ float sInvX[8], sInvY[8], sFa[8];
    __shared__ int sFi[8];
    const int tid = threadIdx.x;
    const int c = tid & 31;
    {
        const int b = tid >> 5;
        float mv = Pmax[tid];
        int mi = Pidx[tid];
        float sx = Psx[tid];
        float sy = Psy[tid];
#pragma unroll
        for (int off = 16; off > 0; off >>= 1) {
            float ov = __shfl_down(mv, off, 32);
            int oi = __shfl_down(mi, off, 32);
            float osx = __shfl_down(sx, off, 32);
            float osy = __shfl_down(sy, off, 32);
            if (ov > mv || (ov == mv && oi < mi)) { mv = ov; mi = oi; }
            sx += osx;
            sy += osy;
        }
        if (c == 0) {
            float fa = (mv < EPSV) ? (EPSV - mv) : 0.0f;
            sFa[b] = fa;
            sFi[b] = mi;
            sInvX[b] = 1.0f / (sx + fa);
            sInvY[b] = 1.0f / sy;
        }
    }
    __syncthreads();
    const int p = blockIdx.x * 256 + tid;
    float z[8];
#pragma unroll
    for (int b = 0; b < 8; ++b) {
        float s = Xs[(size_t)b * HW + p];
        if (p == sFi[b]) s += sFa[b];
        z[b] = s * sInvX[b] - Y[(size_t)b * 3 * HW + p] * sInvY[b];
    }
    Zh[p] = make_uint4(packh2(z[0], z[1]), packh2(z[2], z[3]),
                       packh2(z[4], z[5]), packh2(z[6], z[7]));
}

// Two blocks per projection (half h owns sorted positions [h*8192,(h+1)*8192)).
// Phase 1 (register-window ranksort): thread (g,j2) reads ce over exactly the
// two 16-ranges its sliding window touches -- A=[16g,16g+16) (removals) and
// B=[16g+128,16g+144) (additions) -- keeps the clamped values in registers,
// publishes two 16-granular range sums to psum, window-inits from 8 broadcast
// psum reads, then slides 16 steps in pure register arithmetic. Ties fold into
// the B-loop as a register bitmask (no shared flag, no race). ~67 LDS ops vs
// r14's ~120; no 64KB Ptab. Phase 2: one 16B fp16x8 gather per pixel,
// single-pass 8-channel register scan; cross-half carry via sum(Z)=0.
__global__ __launch_bounds__(1024)
__attribute__((amdgpu_waves_per_eu(4, 4)))
void wproj_kernel(const float* __restrict__ proj,
                  const uint4* __restrict__ Zh,
                  float* __restrict__ out) {
    __shared__ int ce[255];                 // c*2 | e  (c = clamped ceil(d*r))
    __shared__ int psum[16 * 128];          // (run<<5 | tcnt) per (range, j2)
    __shared__ unsigned short sidT[8192];   // own half, [(q&7)*1024 + (q>>3)]
    __shared__ float4 lwa[17], lwb[17];
    __shared__ float lred[16];
    __shared__ int sBound;                  // pixel id at global sorted pos 8192

    const int jp = blockIdx.x >> 1;
    const int h = blockIdx.x & 1;
    const int tid = threadIdx.x, lane = tid & 63, wid = tid >> 6;
    float a = proj[jp];
    float b = proj[NPROJ + jp];
    float inv = 1.0f / sqrtf(a * a + b * b);
    const float an = a * inv, bn = b * inv;
    const float ap = fabsf(an), bp = fabsf(bn);
    const bool flipi = (an < 0.0f), flipj = (bn < 0.0f);

    if (bp == 0.0f) {
        for (int t = tid; t < HW; t += 1024) {
            int i2 = t >> 7, j2 = t & 127;
            int ii = flipi ? 127 - i2 : i2;
            int jj = flipj ? 127 - j2 : j2;
            int idv = ii * 128 + jj;
            if (t == 8192) sBound = idv;
            int q = t - (h << 13);
            if ((unsigned)q < 8192u)
                sidT[(q & 7) * 1024 + (q >> 3)] = (unsigned short)idv;
        }
        __syncthreads();
    } else {
        if (tid < 255) {
            int d = tid - 127;
            double v = (double)d * ((double)ap / (double)bp);
            double cv = ceil(v);
            int e = (cv == v) ? 1 : 0;
            int c = (int)fmin(fmax(cv, -128.0), 129.0);
            ce[tid] = c * 2 + e;   // c = val>>1 (arith), e = val&1
        }
        __syncthreads();

        const int j2 = tid & 127;
        const int g = tid >> 7;          // 0..7
        const int jj = flipj ? 127 - j2 : j2;

        // B1: clamp values for ranges A=[16g,16g+16), B=[16g+128,16g+144)
        // kept in registers; two range sums -> psum; ties as register bitmask.
        int clA[16], clB[16];
        int tmask = 0, tcnt = 0;
        {
            int runA = 0, runB = 0;
            const int ddA0 = g * 16;
            const int ddB0 = g * 16 + 128;
#pragma unroll
            for (int q = 0; q < 16; ++q) {
                int vA = ce[ddA0 + q];
                int cA = min(max((vA >> 1) + j2, 0), 128);
                clA[q] = cA;
                runA += cA;
                int dd = ddB0 + q;
                int cB = 0;
                if (dd < 255) {
                    int vB = ce[dd];
                    cB = min(max((vB >> 1) + j2, 0), 128);
                    if (vB & 1) {   // tie at i2p = dd-127 = 16g+1+q (<=127 since dd<255)
                        int tj = j2 + (vB >> 1);
                        if (tj >= 0 && tj < 128) { tmask |= (1 << (q + 1)); tcnt++; }
                    }
                }
                clB[q] = cB;
                runB += cB;
            }
            psum[g * 128 + j2] = runA << 5;                 // range g (A-type)
            psum[(g + 8) * 128 + j2] = (runB << 5) | tcnt;  // range g+8 (B-type)
        }
        __syncthreads();

        // B2: window init + tie carry from 8 broadcast reads
        // wsum(16g) = sum of range sums r in [g, g+8); carryT from r in [8, g+8)
        int wsum = 0, carryT = 0;
        for (int r = g; r < g + 8; ++r) {
            int v = psum[r * 128 + j2];
            wsum += (v >> 5);
            if (r >= 8) carryT += (v & 31);
        }

        // D: ranks for i2 in [16g, 16g+16), pure register slide
        int tsum = carryT;
        const int i2s = g * 16;
#pragma unroll
        for (int q = 0; q < 16; ++q) {
            int i2 = i2s + q;
            if (q > 0) {
                wsum += clB[q - 1] - clA[q - 1];  // add cl(i2+127), drop cl(i2-1)
                tsum += (tmask >> q) & 1;
            }
            int pos = wsum + tsum;
            int ii = flipi ? 127 - i2 : i2;
            int idv = ii * 128 + jj;
            if (pos == 8192) sBound = idv;
            int ql = pos - (h << 13);
            if ((unsigned)ql < 8192u)
                sidT[(ql & 7) * 1024 + (ql >> 3)] = (unsigned short)idv;
        }
        __syncthreads();
    }

    // ---- phase 2: thread owns local positions [8*tid, 8*tid+7] ----
    int ids[9];
#pragma unroll
    for (int m = 0; m < 8; ++m) ids[m] = (int)sidT[m * 1024 + tid];
    ids[8] = (tid < 1023) ? (int)sidT[tid + 1]
                          : ((h == 0) ? sBound : ids[7]);  // h==1 tail: dpc[7]=0

    float dpc[8];
    {
        float pc_cur = (float)(ids[0] >> 7) * an + (float)(ids[0] & 127) * bn;
#pragma unroll
        for (int m = 0; m < 8; ++m) {
            int idn = ids[m + 1];
            float pc_nxt = (float)(idn >> 7) * an + (float)(idn & 127) * bn;
            dpc[m] = pc_nxt - pc_cur;
            pc_cur = pc_nxt;
        }
    }

    // single 16B gather per pixel; unpack to 8-channel register state
    float4 zva[8], zvb[8];
#pragma unroll
    for (int m = 0; m < 8; ++m) {
        uint4 rr = Zh[ids[m]];
        float2 f0 = unpackh2(rr.x);
        float2 f1 = unpackh2(rr.y);
        float2 f2 = unpackh2(rr.z);
        float2 f3 = unpackh2(rr.w);
        zva[m] = make_float4(f0.x, f0.y, f1.x, f1.y);
        zvb[m] = make_float4(f2.x, f2.y, f3.x, f3.y);
    }
#pragma unroll
    for (int m = 1; m < 8; ++m) {
        zva[m] = add4(zva[m], zva[m - 1]);
        zvb[m] = add4(zvb[m], zvb[m - 1]);
    }
    const float4 tota = zva[7], totb = zvb[7];

    float4 ia = tota, ib = totb;
#pragma unroll
    for (int off = 1; off < 64; off <<= 1) {
        float4 ua = shfl_up4(ia, off);
        float4 ub = shfl_up4(ib, off);
        if (lane >= off) { ia = add4(ia, ua); ib = add4(ib, ub); }
    }
    if (lane == 63) { lwa[wid] = ia; lwb[wid] = ib; }
    __syncthreads();
    if (tid < 16) {  // second-level 16-lane scan of wave totals
        float4 va = lwa[tid], vb = lwb[tid];
        float4 sa = va, sb = vb;
#pragma unroll
        for (int off = 1; off < 16; off <<= 1) {
            float4 ua = shfl_up4w(sa, off, 16);
            float4 ub = shfl_up4w(sb, off, 16);
            if (tid >= off) { sa = add4(sa, ua); sb = add4(sb, ub); }
        }
        lwa[tid] = sub4(sa, va);       // exclusive
        lwb[tid] = sub4(sb, vb);
        if (tid == 15) { lwa[16] = sa; lwb[16] = sb; }  // block totals
    }
    __syncthreads();

    float4 preA = add4(sub4(ia, tota), lwa[wid]);
    float4 preB = add4(sub4(ib, totb), lwb[wid]);
    if (h == 1) {  // carry = total(h0) = -total(h1)
        preA = sub4(preA, lwa[16]);
        preB = sub4(preB, lwb[16]);
    }

    float acc = 0.0f;
#pragma unroll
    for (int m = 0; m < 8; ++m) {
        float4 cxa = add4(preA, zva[m]);
        float4 cxb = add4(preB, zvb[m]);
        float s8 = fabsf(cxa.x) + fabsf(cxa.y) + fabsf(cxa.z) + fabsf(cxa.w)
                 + fabsf(cxb.x) + fabsf(cxb.y) + fabsf(cxb.z) + fabsf(cxb.w);
        acc += s8 * dpc[m];
    }

    // block reduce
#pragma unroll
    for (int off = 32; off > 0; off >>= 1) acc += __shfl_down(acc, off);
    if (lane == 0) lred[wid] = acc;
    __syncthreads();
    if (tid == 0) {
        float r2 = 0.0f;
        for (int w = 0; w < 16; ++w) r2 += lred[w];
        atomicAdd(out, r2 * (1.0f / NPROJ));
    }
}

extern "C" void kernel_launch(void* const* d_in, const int* in_sizes, int n_in,
                              void* d_out, int out_size, void* d_ws, size_t ws_size,
                              hipStream_t stream) {
    const float* X = (const float*)d_in[0];
    const float* Y = (const float*)d_in[1];
    const float* proj = (const float*)d_in[2];
    float* out = (float*)d_out;

    char* ws = (char*)d_ws;
    size_t off = 0;
    float* Xs = (float*)(ws + off);     off += (size_t)NB * HW * sizeof(float);
    uint4* Zh = (uint4*)(ws + off);     off += (size_t)HW * sizeof(uint4);
    float* Pmax = (float*)(ws + off);   off += NB * NCH * sizeof(float);
    int* Pidx = (int*)(ws + off);       off += NB * NCH * sizeof(int);
    float* Psx = (float*)(ws + off);    off += NB * NCH * sizeof(float);
    float* Psy = (float*)(ws + off);    off += NB * NCH * sizeof(float);

    partial_kernel<<<NB * NCH, 256, 0, stream>>>(X, Y, Xs, Pmax, Pidx, Psx, Psy, out);
    zprep_kernel<<<HW / 256, 256, 0, stream>>>(Pmax, Pidx, Psx, Psy, Xs, Y, Zh);
    wproj_kernel<<<NPROJ * 2, 1024, 0, stream>>>(proj, Zh, out);
}